// Round 1
// baseline (1670.004 us; speedup 1.0000x reference)
//
#include <hip/hip_runtime.h>
#include <math.h>

#define BB 32
#define NPGC 256
#define FF 128
#define EDIMC 16
#define ESMC 1280
#define NNODE 8192
#define NEDGE 65536
#define NH 4
#define DH 128
#define HDIM 512
#define WE_ELEMS (EDIMC * HDIM)

// ---------------- utility ----------------
__device__ __forceinline__ float waveReduceSum(float v) {
#pragma unroll
    for (int o = 32; o > 0; o >>= 1) v += __shfl_down(v, o);
    return v;
}

// ---------------- init ----------------
__global__ void k_init(int* __restrict__ emask, int* __restrict__ nmask) {
    int i = blockIdx.x * 256 + threadIdx.x;
    if (i < NEDGE) emask[i] = 1;
    if (i < NNODE) nmask[i] = 1;
}

// ---------------- CSR build (by dst) ----------------
__global__ void k_count(const int* __restrict__ dst, int* __restrict__ indeg) {
    int e = blockIdx.x * 256 + threadIdx.x;
    if (e < NEDGE) atomicAdd(&indeg[dst[e]], 1);
}

__global__ __launch_bounds__(256) void k_scan(const int* __restrict__ indeg, int* __restrict__ off) {
    __shared__ int part[256];
    __shared__ int pref[257];
    int t = threadIdx.x;
    int base = t * 32;
    int loc[32];
    int s = 0;
#pragma unroll
    for (int j = 0; j < 32; ++j) { loc[j] = s; s += indeg[base + j]; }
    part[t] = s;
    __syncthreads();
    if (t == 0) {
        int a = 0;
        for (int j = 0; j < 256; ++j) { pref[j] = a; a += part[j]; }
        pref[256] = a;
    }
    __syncthreads();
#pragma unroll
    for (int j = 0; j < 32; ++j) off[base + j] = pref[t] + loc[j];
    if (t == 255) off[NNODE] = pref[256];
}

__global__ void k_scatter(const int* __restrict__ dst, const int* __restrict__ off,
                          int* __restrict__ cnt, int* __restrict__ eid) {
    int e = blockIdx.x * 256 + threadIdx.x;
    if (e < NEDGE) {
        int d = dst[e];
        int pos = atomicAdd(&cnt[d], 1);
        eid[off[d] + pos] = e;
    }
}

// ---------------- tiled fp32 GEMM ----------------
// C = A(MxK) @ W(KxN) + bias, with optional relu+BN epilogue (EPI==1).
// blockIdx.z selects among up to 4 (W,b,C) sets (for fused q/k/v/skip).
template <int BM, int BN, int BK, int TM, int TN, int EPI>
__global__ __launch_bounds__(256) void k_gemm(
    const float* __restrict__ A,
    const float* W0, const float* W1, const float* W2, const float* W3,
    const float* b0, const float* b1, const float* b2, const float* b3,
    float* C0, float* C1, float* C2, float* C3,
    int M, int N, int K,
    const float* __restrict__ gam, const float* __restrict__ bet,
    const float* __restrict__ rme, const float* __restrict__ rva) {
    const float* Wsel;
    const float* bsel;
    float* Csel;
    if (blockIdx.z == 0) { Wsel = W0; bsel = b0; Csel = C0; }
    else if (blockIdx.z == 1) { Wsel = W1; bsel = b1; Csel = C1; }
    else if (blockIdx.z == 2) { Wsel = W2; bsel = b2; Csel = C2; }
    else { Wsel = W3; bsel = b3; Csel = C3; }

    __shared__ float As[BK][BM + 4];  // transposed A tile; +4 pad keeps 16B align + low conflicts
    __shared__ float Ws[BK][BN];

    constexpr int TX = BN / TN;
    constexpr int TY = BM / TM;
    static_assert(TX * TY == 256, "bad tile config");
    int tid = threadIdx.x;
    int tx = tid % TX, ty = tid / TX;
    int row0 = blockIdx.x * BM, col0 = blockIdx.y * BN;

    float acc[TM][TN] = {};

    for (int k0 = 0; k0 < K; k0 += BK) {
        constexpr int ALOADS = (BM * BK) / (256 * 4);
#pragma unroll
        for (int i = 0; i < ALOADS; ++i) {
            int idx = (tid + i * 256) * 4;
            int r = idx / BK, c = idx % BK;
            float4 val = *(const float4*)(A + (size_t)(row0 + r) * K + k0 + c);
            As[c + 0][r] = val.x;
            As[c + 1][r] = val.y;
            As[c + 2][r] = val.z;
            As[c + 3][r] = val.w;
        }
        constexpr int WLOADS = (BK * BN) / (256 * 4);
#pragma unroll
        for (int i = 0; i < WLOADS; ++i) {
            int idx = (tid + i * 256) * 4;
            int r = idx / BN, c = idx % BN;
            *(float4*)&Ws[r][c] = *(const float4*)(Wsel + (size_t)(k0 + r) * N + col0 + c);
        }
        __syncthreads();
#pragma unroll
        for (int kk = 0; kk < BK; ++kk) {
            float ra[TM], rb[TN];
#pragma unroll
            for (int i = 0; i < TM; i += 4) *(float4*)&ra[i] = *(const float4*)&As[kk][ty * TM + i];
#pragma unroll
            for (int j = 0; j < TN; j += 4) *(float4*)&rb[j] = *(const float4*)&Ws[kk][tx * TN + j];
#pragma unroll
            for (int i = 0; i < TM; ++i)
#pragma unroll
                for (int j = 0; j < TN; ++j) acc[i][j] = fmaf(ra[i], rb[j], acc[i][j]);
        }
        __syncthreads();
    }

#pragma unroll
    for (int i = 0; i < TM; ++i) {
        size_t r = row0 + ty * TM + i;
#pragma unroll
        for (int j0 = 0; j0 < TN; j0 += 4) {
            float4 o;
            float* op = &o.x;
#pragma unroll
            for (int j = 0; j < 4; ++j) {
                int c = col0 + tx * TN + j0 + j;
                float val = acc[i][j0 + j] + bsel[c];
                if constexpr (EPI == 1) {
                    val = fmaxf(val, 0.f);
                    val = (val - rme[c]) * rsqrtf(rva[c] + 1e-5f) * gam[c] + bet[c];
                }
                op[j] = val;
            }
            *(float4*)(Csel + r * N + col0 + tx * TN + j0) = o;
        }
    }
}

// ---------------- edge attention scores ----------------
// a[e][h] = scale * sum_d q[dst][h][d] * (k[src][h][d] + (edge_attr[e] @ We)[h][d])
__global__ __launch_bounds__(256) void k_edge_scores(
    const float* __restrict__ q, const float* __restrict__ kmat,
    const float* __restrict__ eattr, const float* __restrict__ We,
    const int* __restrict__ src, const int* __restrict__ dst,
    const int* __restrict__ emask, float* __restrict__ a_sc) {
    __shared__ float WeS[WE_ELEMS];
    for (int i = threadIdx.x; i < WE_ELEMS / 4; i += 256)
        ((float4*)WeS)[i] = ((const float4*)We)[i];
    __syncthreads();
    int wave = threadIdx.x >> 6, lane = threadIdx.x & 63;
#pragma unroll
    for (int rep = 0; rep < 4; ++rep) {
        int eid = blockIdx.x * 16 + wave * 4 + rep;
        if (!emask[eid]) continue;  // wave-uniform branch
        int sn = src[eid], dn = dst[eid];
        float ea[EDIMC];
#pragma unroll
        for (int j = 0; j < EDIMC; ++j) ea[j] = eattr[(size_t)eid * EDIMC + j];
        const float* qrow = q + (size_t)dn * HDIM;
        const float* krow = kmat + (size_t)sn * HDIM;
#pragma unroll
        for (int h = 0; h < NH; ++h) {
            float acc = 0.f;
#pragma unroll
            for (int half = 0; half < 2; ++half) {
                int dd = h * DH + half * 64 + lane;
                float ev = 0.f;
#pragma unroll
                for (int j = 0; j < EDIMC; ++j) ev = fmaf(ea[j], WeS[j * HDIM + dd], ev);
                acc = fmaf(qrow[dd], krow[dd] + ev, acc);
            }
            acc = waveReduceSum(acc);
            if (lane == 0) a_sc[(size_t)eid * NH + h] = acc * 0.088388347648318447f;  // 1/sqrt(128)
        }
    }
}

// ---------------- per (node, head) softmax max + denom ----------------
__global__ void k_softmax_md(const float* __restrict__ a_sc, const int* __restrict__ coff,
                             const int* __restrict__ ceid, const int* __restrict__ emask,
                             float* __restrict__ mbuf, float* __restrict__ dbuf) {
    int t = blockIdx.x * 256 + threadIdx.x;  // NN*NH threads
    if (t >= NNODE * NH) return;
    int n = t >> 2, h = t & 3;
    int o0 = coff[n], o1 = coff[n + 1];
    float m = -1e30f;
    for (int j = o0; j < o1; ++j) {
        int e = ceid[j];
        if (!emask[e]) continue;
        m = fmaxf(m, a_sc[(size_t)e * NH + h]);
    }
    float den = 0.f;
    for (int j = o0; j < o1; ++j) {
        int e = ceid[j];
        if (!emask[e]) continue;
        den += expf(a_sc[(size_t)e * NH + h] - m);
    }
    mbuf[t] = m;
    dbuf[t] = den;
}

// ---------------- message aggregation per node ----------------
// out[n][d] = sum_{e: dst(e)=n, emask} attn[e][h(d)] * (v[src(e)][d] + eproj[e][d])
__global__ __launch_bounds__(256) void k_aggregate(
    const float* __restrict__ vmat, const float* __restrict__ eattr,
    const float* __restrict__ We, const float* __restrict__ a_sc,
    const float* __restrict__ mbuf, const float* __restrict__ dbuf,
    const int* __restrict__ src, const int* __restrict__ coff,
    const int* __restrict__ ceid, const int* __restrict__ emask,
    float* __restrict__ out) {
    __shared__ float WeS[WE_ELEMS];
    for (int i = threadIdx.x; i < WE_ELEMS / 4; i += 256)
        ((float4*)WeS)[i] = ((const float4*)We)[i];
    __syncthreads();
    int n = blockIdx.x, t = threadIdx.x;
    int d0 = t, d1 = t + 256;
    int h0 = d0 >> 7, h1 = d1 >> 7;
    float m0 = mbuf[n * NH + h0], m1 = mbuf[n * NH + h1];
    float de0 = fmaxf(dbuf[n * NH + h0], 1e-16f);
    float de1 = fmaxf(dbuf[n * NH + h1], 1e-16f);
    float acc0 = 0.f, acc1 = 0.f;
    int o0 = coff[n], o1 = coff[n + 1];
    for (int jj = o0; jj < o1; ++jj) {
        int e = ceid[jj];
        if (!emask[e]) continue;
        int s = src[e];
        float at0 = expf(a_sc[(size_t)e * NH + h0] - m0) / de0;
        float at1 = expf(a_sc[(size_t)e * NH + h1] - m1) / de1;
        float e0 = 0.f, e1 = 0.f;
#pragma unroll
        for (int j = 0; j < EDIMC; ++j) {
            float w = eattr[(size_t)e * EDIMC + j];
            e0 = fmaf(w, WeS[j * HDIM + d0], e0);
            e1 = fmaf(w, WeS[j * HDIM + d1], e1);
        }
        acc0 = fmaf(vmat[(size_t)s * HDIM + d0] + e0, at0, acc0);
        acc1 = fmaf(vmat[(size_t)s * HDIM + d1] + e1, at1, acc1);
    }
    out[(size_t)n * HDIM + d0] = acc0;
    out[(size_t)n * HDIM + d1] = acc1;
}

// ---------------- beta gate ----------------
__global__ __launch_bounds__(256) void k_beta(const float* __restrict__ ao,
                                              const float* __restrict__ xr,
                                              const float* __restrict__ Wb,
                                              float* __restrict__ bta) {
    int wave = threadIdx.x >> 6, lane = threadIdx.x & 63;
    int n = blockIdx.x * 4 + wave;
    const float* o = ao + (size_t)n * HDIM;
    const float* r = xr + (size_t)n * HDIM;
    float acc = 0.f;
#pragma unroll
    for (int i0 = 0; i0 < HDIM; i0 += 64) {
        int i = i0 + lane;
        float ov = o[i], rv = r[i];
        acc += ov * Wb[i] + rv * Wb[HDIM + i] + (ov - rv) * Wb[2 * HDIM + i];
    }
    acc = waveReduceSum(acc);
    if (lane == 0) bta[n] = 1.f / (1.f + expf(-acc));
}

__global__ void k_h2(const float* __restrict__ ao, const float* __restrict__ xr,
                     const float* __restrict__ bta, float* __restrict__ h2) {
    int i = blockIdx.x * 256 + threadIdx.x;  // NN*HDIM
    float b = bta[i >> 9];
    h2[i] = b * xr[i] + (1.f - b) * ao[i];
}

// ---------------- TopK pooling ----------------
__global__ __launch_bounds__(256) void k_pool_score(const float* __restrict__ h,
                                                    const float* __restrict__ w,
                                                    float* __restrict__ sv) {
    int wave = threadIdx.x >> 6, lane = threadIdx.x & 63;
    int n = blockIdx.x * 4 + wave;
    float w0 = w[lane], w1 = w[lane + 64];
    float n2 = waveReduceSum(w0 * w0 + w1 * w1);
    float dv = h[(size_t)n * FF + lane] * w0 + h[(size_t)n * FF + lane + 64] * w1;
    dv = waveReduceSum(dv);
    if (lane == 0) sv[n] = tanhf(dv / sqrtf(n2));
}

__global__ __launch_bounds__(256) void k_pool_rank(const float* __restrict__ sv,
                                                   int* __restrict__ nmask,
                                                   int* __restrict__ keep, int kc) {
    __shared__ float sm[NPGC];
    int g = blockIdx.x, t = threadIdx.x;
    int n = g * NPGC + t;
    int old = nmask[n];
    sm[t] = old ? sv[n] : -INFINITY;
    __syncthreads();
    float mys = sm[t];
    int rank = 0;
    for (int j = 0; j < NPGC; ++j) {
        float o = sm[j];
        rank += (o > mys) || (o == mys && j < t);  // stable argsort tie-break
    }
    int kp = (rank < kc) && old;
    keep[n] = kp;
    nmask[n] = kp;
}

__global__ void k_pool_scale(float* __restrict__ h, const float* __restrict__ sv,
                             const int* __restrict__ keep) {
    int i = blockIdx.x * 256 + threadIdx.x;  // NN*FF
    int n = i >> 7;
    h[i] *= sv[n] * (float)keep[n];
}

__global__ void k_emask_upd(int* __restrict__ emask, const int* __restrict__ keep,
                            const int* __restrict__ src, const int* __restrict__ dst) {
    int e = blockIdx.x * 256 + threadIdx.x;
    if (e < NEDGE) emask[e] = emask[e] && keep[src[e]] && keep[dst[e]];
}

__global__ __launch_bounds__(128) void k_readout(const float* __restrict__ h,
                                                 const int* __restrict__ keep,
                                                 float* __restrict__ rep) {
    int g = blockIdx.x, d = threadIdx.x;  // 128 threads = F dims
    float mx = -1e30f, smv = 0.f;
    int cnt = 0;
    for (int j = 0; j < NPGC; ++j) {
        int n = g * NPGC + j;
        int kp = keep[n];
        float val = h[(size_t)n * FF + d];
        if (kp) { mx = fmaxf(mx, val); smv += val; cnt++; }
    }
    rep[(size_t)g * 256 + d] = mx;
    rep[(size_t)g * 256 + 128 + d] = smv / fmaxf((float)cnt, 1.f);
}

// ---------------- readout head ----------------
__global__ void k_build_g(const float* __restrict__ r0, const float* __restrict__ r1,
                          const float* __restrict__ esm, float* __restrict__ g1) {
    int i = blockIdx.x * 256 + threadIdx.x;  // BB*1536
    int r = i / 1536, c = i % 1536;
    g1[i] = (c < 256) ? (r0[r * 256 + c] + r1[r * 256 + c]) : esm[r * ESMC + (c - 256)];
}

__global__ void k_mlp(const float* __restrict__ A, const float* __restrict__ W,
                      const float* __restrict__ b, float* __restrict__ C,
                      int M, int N, int K, int relu) {
    int i = blockIdx.x * 256 + threadIdx.x;
    if (i >= M * N) return;
    int r = i / N, c = i % N;
    float acc = b[c];
    for (int kk = 0; kk < K; ++kk) acc = fmaf(A[(size_t)r * K + kk], W[(size_t)kk * N + c], acc);
    if (relu) acc = fmaxf(acc, 0.f);
    C[i] = acc;
}

// ---------------- host launch ----------------
extern "C" void kernel_launch(void* const* d_in, const int* in_sizes, int n_in,
                              void* d_out, int out_size, void* d_ws, size_t ws_size,
                              hipStream_t stream) {
    const float* x = (const float*)d_in[0];
    const float* eattr = (const float*)d_in[1];
    const int* eidx = (const int*)d_in[2];
    const float* esm = (const float*)d_in[4];
    const float* Wq = (const float*)d_in[5];
    const float* bq = (const float*)d_in[6];
    const float* Wk = (const float*)d_in[7];
    const float* bk = (const float*)d_in[8];
    const float* Wv = (const float*)d_in[9];
    const float* bv = (const float*)d_in[10];
    const float* We = (const float*)d_in[11];
    const float* Wsk = (const float*)d_in[12];
    const float* bsk = (const float*)d_in[13];
    const float* Wbe = (const float*)d_in[14];
    const float* Wt = (const float*)d_in[15];
    const float* bt = (const float*)d_in[16];
    const float* gam = (const float*)d_in[17];
    const float* bet = (const float*)d_in[18];
    const float* rme = (const float*)d_in[19];
    const float* rva = (const float*)d_in[20];
    const float* pw = (const float*)d_in[21];
    const float* W1 = (const float*)d_in[22];
    const float* b1 = (const float*)d_in[23];
    const float* W2 = (const float*)d_in[24];
    const float* b2 = (const float*)d_in[25];
    const float* W3 = (const float*)d_in[26];
    const float* b3 = (const float*)d_in[27];
    const int* srcp = eidx;
    const int* dstp = eidx + NEDGE;

    char* p = (char*)d_ws;
    auto alloc = [&](size_t bytes) -> void* {
        void* r = (void*)p;
        p += (bytes + 255) & ~(size_t)255;
        return r;
    };
    float* hA = (float*)alloc((size_t)NNODE * FF * 4);
    float* hB = (float*)alloc((size_t)NNODE * FF * 4);
    float* qb = (float*)alloc((size_t)NNODE * HDIM * 4);
    float* kb = (float*)alloc((size_t)NNODE * HDIM * 4);
    float* vb = (float*)alloc((size_t)NNODE * HDIM * 4);
    float* xrb = (float*)alloc((size_t)NNODE * HDIM * 4);
    float* aob = (float*)alloc((size_t)NNODE * HDIM * 4);
    float* h2b = qb;  // q no longer needed once scores are done
    float* a_sc = (float*)alloc((size_t)NEDGE * NH * 4);
    float* mb = (float*)alloc((size_t)NNODE * NH * 4);
    float* db = (float*)alloc((size_t)NNODE * NH * 4);
    float* btab = (float*)alloc((size_t)NNODE * 4);
    float* sv = (float*)alloc((size_t)NNODE * 4);
    float* rep0 = (float*)alloc((size_t)BB * 256 * 4);
    float* rep1 = (float*)alloc((size_t)BB * 256 * 4);
    float* g1 = (float*)alloc((size_t)BB * 1536 * 4);
    float* g2 = (float*)alloc((size_t)BB * 512 * 4);
    float* g3 = (float*)alloc((size_t)BB * 256 * 4);
    int* nmask = (int*)alloc((size_t)NNODE * 4);
    int* emask = (int*)alloc((size_t)NEDGE * 4);
    int* keep = (int*)alloc((size_t)NNODE * 4);
    int* indeg = (int*)alloc((size_t)NNODE * 4);
    int* coff = (int*)alloc((size_t)(NNODE + 1) * 4);
    int* ccnt = (int*)alloc((size_t)NNODE * 4);
    int* ceid = (int*)alloc((size_t)NEDGE * 4);

    hipMemsetAsync(indeg, 0, (size_t)NNODE * 4, stream);
    hipMemsetAsync(ccnt, 0, (size_t)NNODE * 4, stream);
    k_init<<<NEDGE / 256, 256, 0, stream>>>(emask, nmask);
    k_count<<<NEDGE / 256, 256, 0, stream>>>(dstp, indeg);
    k_scan<<<1, 256, 0, stream>>>(indeg, coff);
    k_scatter<<<NEDGE / 256, 256, 0, stream>>>(dstp, coff, ccnt, ceid);

    auto conv = [&](int li, const float* hin, float* hout) {
        size_t wOff = (size_t)li * FF * HDIM;
        dim3 gq(NNODE / 128, HDIM / 128, 4);
        k_gemm<128, 128, 32, 8, 8, 0><<<gq, 256, 0, stream>>>(
            hin, Wq + wOff, Wk + wOff, Wv + wOff, Wsk + wOff,
            bq + li * HDIM, bk + li * HDIM, bv + li * HDIM, bsk + li * HDIM,
            qb, kb, vb, xrb, NNODE, HDIM, FF,
            nullptr, nullptr, nullptr, nullptr);
        const float* WeL = We + (size_t)li * EDIMC * HDIM;
        k_edge_scores<<<NEDGE / 16, 256, 0, stream>>>(qb, kb, eattr, WeL, srcp, dstp, emask, a_sc);
        k_softmax_md<<<NNODE * NH / 256, 256, 0, stream>>>(a_sc, coff, ceid, emask, mb, db);
        k_aggregate<<<NNODE, 256, 0, stream>>>(vb, eattr, WeL, a_sc, mb, db, srcp, coff, ceid,
                                               emask, aob);
        k_beta<<<NNODE / 4, 256, 0, stream>>>(aob, xrb, Wbe + (size_t)li * 3 * HDIM, btab);
        k_h2<<<NNODE * HDIM / 256, 256, 0, stream>>>(aob, xrb, btab, h2b);
        dim3 go(NNODE / 64, FF / 64, 1);
        k_gemm<64, 64, 32, 4, 4, 1><<<go, 256, 0, stream>>>(
            h2b, Wt + (size_t)li * HDIM * FF, nullptr, nullptr, nullptr,
            bt + li * FF, nullptr, nullptr, nullptr,
            hout, nullptr, nullptr, nullptr, NNODE, FF, HDIM,
            gam + li * FF, bet + li * FF, rme + li * FF, rva + li * FF);
    };

    auto pool = [&](int pi, float* h, float* rep, int kc, bool updEmask) {
        k_pool_score<<<NNODE / 4, 256, 0, stream>>>(h, pw + pi * FF, sv);
        k_pool_rank<<<BB, 256, 0, stream>>>(sv, nmask, keep, kc);
        k_pool_scale<<<NNODE * FF / 256, 256, 0, stream>>>(h, sv, keep);
        if (updEmask) k_emask_upd<<<NEDGE / 256, 256, 0, stream>>>(emask, keep, srcp, dstp);
        k_readout<<<BB, 128, 0, stream>>>(h, keep, rep);
    };

    // layer 4 (li=4) is dead code in the reference (its output feeds nothing) — skipped.
    conv(0, x, hA);
    conv(1, hA, hB);
    pool(0, hB, rep0, NPGC / 2, true);
    conv(2, hB, hA);
    conv(3, hA, hB);
    pool(1, hB, rep1, NPGC / 4, false);  // emask update after pool-1 is also dead

    k_build_g<<<BB * 1536 / 256, 256, 0, stream>>>(rep0, rep1, esm, g1);
    k_mlp<<<BB * 512 / 256, 256, 0, stream>>>(g1, W1, b1, g2, BB, 512, 1536, 1);
    k_mlp<<<BB * 256 / 256, 256, 0, stream>>>(g2, W2, b2, g3, BB, 256, 512, 1);
    k_mlp<<<2, 256, 0, stream>>>(g3, W3, b3, (float*)d_out, BB, 10, 256, 0);
}

// Round 2
// 1226.376 us; speedup vs baseline: 1.3617x; 1.3617x over previous
//
#include <hip/hip_runtime.h>
#include <math.h>

#define BB 32
#define NPGC 256
#define FF 128
#define EDIMC 16
#define ESMC 1280
#define NNODE 8192
#define NEDGE 65536
#define NH 4
#define DH 128
#define HDIM 512
#define WE_ELEMS (EDIMC * HDIM)

// ---------------- utility ----------------
__device__ __forceinline__ float waveReduceSum(float v) {
#pragma unroll
    for (int o = 32; o > 0; o >>= 1) v += __shfl_down(v, o);
    return v;
}

// ---------------- init ----------------
__global__ void k_init(int* __restrict__ emask, int* __restrict__ nmask) {
    int i = blockIdx.x * 256 + threadIdx.x;
    if (i < NEDGE) emask[i] = 1;
    if (i < NNODE) nmask[i] = 1;
}

// ---------------- CSR build (by dst) ----------------
__global__ void k_count(const int* __restrict__ dst, int* __restrict__ indeg) {
    int e = blockIdx.x * 256 + threadIdx.x;
    if (e < NEDGE) atomicAdd(&indeg[dst[e]], 1);
}

__global__ __launch_bounds__(256) void k_scan(const int* __restrict__ indeg, int* __restrict__ off) {
    __shared__ int part[256];
    __shared__ int pref[257];
    int t = threadIdx.x;
    int base = t * 32;
    int loc[32];
    int s = 0;
#pragma unroll
    for (int j = 0; j < 32; ++j) { loc[j] = s; s += indeg[base + j]; }
    part[t] = s;
    __syncthreads();
    if (t == 0) {
        int a = 0;
        for (int j = 0; j < 256; ++j) { pref[j] = a; a += part[j]; }
        pref[256] = a;
    }
    __syncthreads();
#pragma unroll
    for (int j = 0; j < 32; ++j) off[base + j] = pref[t] + loc[j];
    if (t == 255) off[NNODE] = pref[256];
}

__global__ void k_scatter(const int* __restrict__ dst, const int* __restrict__ off,
                          int* __restrict__ cnt, int* __restrict__ eid) {
    int e = blockIdx.x * 256 + threadIdx.x;
    if (e < NEDGE) {
        int d = dst[e];
        int pos = atomicAdd(&cnt[d], 1);
        eid[off[d] + pos] = e;
    }
}

// ---------------- tiled fp32 GEMM ----------------
// C = A(MxK) @ W(KxN) + bias, with optional relu+BN epilogue (EPI==1).
// blockIdx.z selects among up to 4 (W,b,C) sets (for fused q/k/v/skip).
template <int BM, int BN, int BK, int TM, int TN, int EPI>
__global__ __launch_bounds__(256) void k_gemm(
    const float* __restrict__ A,
    const float* W0, const float* W1, const float* W2, const float* W3,
    const float* b0, const float* b1, const float* b2, const float* b3,
    float* C0, float* C1, float* C2, float* C3,
    int M, int N, int K,
    const float* __restrict__ gam, const float* __restrict__ bet,
    const float* __restrict__ rme, const float* __restrict__ rva) {
    const float* Wsel;
    const float* bsel;
    float* Csel;
    if (blockIdx.z == 0) { Wsel = W0; bsel = b0; Csel = C0; }
    else if (blockIdx.z == 1) { Wsel = W1; bsel = b1; Csel = C1; }
    else if (blockIdx.z == 2) { Wsel = W2; bsel = b2; Csel = C2; }
    else { Wsel = W3; bsel = b3; Csel = C3; }

    __shared__ float As[BK][BM + 4];  // transposed A tile; +4 pad keeps 16B align + low conflicts
    __shared__ float Ws[BK][BN];

    constexpr int TX = BN / TN;
    constexpr int TY = BM / TM;
    static_assert(TX * TY == 256, "bad tile config");
    int tid = threadIdx.x;
    int tx = tid % TX, ty = tid / TX;
    int row0 = blockIdx.x * BM, col0 = blockIdx.y * BN;

    float acc[TM][TN] = {};

    for (int k0 = 0; k0 < K; k0 += BK) {
        constexpr int ALOADS = (BM * BK) / (256 * 4);
#pragma unroll
        for (int i = 0; i < ALOADS; ++i) {
            int idx = (tid + i * 256) * 4;
            int r = idx / BK, c = idx % BK;
            float4 val = *(const float4*)(A + (size_t)(row0 + r) * K + k0 + c);
            As[c + 0][r] = val.x;
            As[c + 1][r] = val.y;
            As[c + 2][r] = val.z;
            As[c + 3][r] = val.w;
        }
        constexpr int WLOADS = (BK * BN) / (256 * 4);
#pragma unroll
        for (int i = 0; i < WLOADS; ++i) {
            int idx = (tid + i * 256) * 4;
            int r = idx / BN, c = idx % BN;
            *(float4*)&Ws[r][c] = *(const float4*)(Wsel + (size_t)(k0 + r) * N + col0 + c);
        }
        __syncthreads();
#pragma unroll
        for (int kk = 0; kk < BK; ++kk) {
            float ra[TM], rb[TN];
#pragma unroll
            for (int i = 0; i < TM; i += 4) *(float4*)&ra[i] = *(const float4*)&As[kk][ty * TM + i];
#pragma unroll
            for (int j = 0; j < TN; j += 4) *(float4*)&rb[j] = *(const float4*)&Ws[kk][tx * TN + j];
#pragma unroll
            for (int i = 0; i < TM; ++i)
#pragma unroll
                for (int j = 0; j < TN; ++j) acc[i][j] = fmaf(ra[i], rb[j], acc[i][j]);
        }
        __syncthreads();
    }

#pragma unroll
    for (int i = 0; i < TM; ++i) {
        size_t r = row0 + ty * TM + i;
#pragma unroll
        for (int j0 = 0; j0 < TN; j0 += 4) {
            float4 o;
            float* op = &o.x;
#pragma unroll
            for (int j = 0; j < 4; ++j) {
                int c = col0 + tx * TN + j0 + j;
                float val = acc[i][j0 + j] + bsel[c];
                if constexpr (EPI == 1) {
                    val = fmaxf(val, 0.f);
                    val = (val - rme[c]) * rsqrtf(rva[c] + 1e-5f) * gam[c] + bet[c];
                }
                op[j] = val;
            }
            *(float4*)(Csel + r * N + col0 + tx * TN + j0) = o;
        }
    }
}

// ---------------- edge attention scores ----------------
// a[e][h] = scale * sum_d q[dst][h][d] * (k[src][h][d] + (edge_attr[e] @ We)[h][d])
__global__ __launch_bounds__(256) void k_edge_scores(
    const float* __restrict__ q, const float* __restrict__ kmat,
    const float* __restrict__ eattr, const float* __restrict__ We,
    const int* __restrict__ src, const int* __restrict__ dst,
    const int* __restrict__ emask, float* __restrict__ a_sc) {
    __shared__ float WeS[WE_ELEMS];
    for (int i = threadIdx.x; i < WE_ELEMS / 4; i += 256)
        ((float4*)WeS)[i] = ((const float4*)We)[i];
    __syncthreads();
    int wave = threadIdx.x >> 6, lane = threadIdx.x & 63;
#pragma unroll
    for (int rep = 0; rep < 4; ++rep) {
        int eid = blockIdx.x * 16 + wave * 4 + rep;
        if (!emask[eid]) continue;  // wave-uniform branch
        int sn = src[eid], dn = dst[eid];
        float ea[EDIMC];
#pragma unroll
        for (int j = 0; j < EDIMC; ++j) ea[j] = eattr[(size_t)eid * EDIMC + j];
        const float* qrow = q + (size_t)dn * HDIM;
        const float* krow = kmat + (size_t)sn * HDIM;
#pragma unroll
        for (int h = 0; h < NH; ++h) {
            float acc = 0.f;
#pragma unroll
            for (int half = 0; half < 2; ++half) {
                int dd = h * DH + half * 64 + lane;
                float ev = 0.f;
#pragma unroll
                for (int j = 0; j < EDIMC; ++j) ev = fmaf(ea[j], WeS[j * HDIM + dd], ev);
                acc = fmaf(qrow[dd], krow[dd] + ev, acc);
            }
            acc = waveReduceSum(acc);
            if (lane == 0) a_sc[(size_t)eid * NH + h] = acc * 0.088388347648318447f;  // 1/sqrt(128)
        }
    }
}

// ---------------- per (node, head) softmax max + denom ----------------
__global__ void k_softmax_md(const float* __restrict__ a_sc, const int* __restrict__ coff,
                             const int* __restrict__ ceid, const int* __restrict__ emask,
                             float* __restrict__ mbuf, float* __restrict__ dbuf) {
    int t = blockIdx.x * 256 + threadIdx.x;  // NN*NH threads
    if (t >= NNODE * NH) return;
    int n = t >> 2, h = t & 3;
    int o0 = coff[n], o1 = coff[n + 1];
    float m = -1e30f;
    for (int j = o0; j < o1; ++j) {
        int e = ceid[j];
        if (!emask[e]) continue;
        m = fmaxf(m, a_sc[(size_t)e * NH + h]);
    }
    float den = 0.f;
    for (int j = o0; j < o1; ++j) {
        int e = ceid[j];
        if (!emask[e]) continue;
        den += expf(a_sc[(size_t)e * NH + h] - m);
    }
    mbuf[t] = m;
    dbuf[t] = den;
}

// ---------------- message aggregation per node ----------------
// out[n][d] = sum_{e: dst(e)=n, emask} attn[e][h(d)] * (v[src(e)][d] + eproj[e][d])
__global__ __launch_bounds__(256) void k_aggregate(
    const float* __restrict__ vmat, const float* __restrict__ eattr,
    const float* __restrict__ We, const float* __restrict__ a_sc,
    const float* __restrict__ mbuf, const float* __restrict__ dbuf,
    const int* __restrict__ src, const int* __restrict__ coff,
    const int* __restrict__ ceid, const int* __restrict__ emask,
    float* __restrict__ out) {
    __shared__ float WeS[WE_ELEMS];
    for (int i = threadIdx.x; i < WE_ELEMS / 4; i += 256)
        ((float4*)WeS)[i] = ((const float4*)We)[i];
    __syncthreads();
    int n = blockIdx.x, t = threadIdx.x;
    int d0 = t, d1 = t + 256;
    int h0 = d0 >> 7, h1 = d1 >> 7;
    float m0 = mbuf[n * NH + h0], m1 = mbuf[n * NH + h1];
    float de0 = fmaxf(dbuf[n * NH + h0], 1e-16f);
    float de1 = fmaxf(dbuf[n * NH + h1], 1e-16f);
    float acc0 = 0.f, acc1 = 0.f;
    int o0 = coff[n], o1 = coff[n + 1];
    for (int jj = o0; jj < o1; ++jj) {
        int e = ceid[jj];
        if (!emask[e]) continue;
        int s = src[e];
        float at0 = expf(a_sc[(size_t)e * NH + h0] - m0) / de0;
        float at1 = expf(a_sc[(size_t)e * NH + h1] - m1) / de1;
        float e0 = 0.f, e1 = 0.f;
#pragma unroll
        for (int j = 0; j < EDIMC; ++j) {
            float w = eattr[(size_t)e * EDIMC + j];
            e0 = fmaf(w, WeS[j * HDIM + d0], e0);
            e1 = fmaf(w, WeS[j * HDIM + d1], e1);
        }
        acc0 = fmaf(vmat[(size_t)s * HDIM + d0] + e0, at0, acc0);
        acc1 = fmaf(vmat[(size_t)s * HDIM + d1] + e1, at1, acc1);
    }
    out[(size_t)n * HDIM + d0] = acc0;
    out[(size_t)n * HDIM + d1] = acc1;
}

// ---------------- beta gate ----------------
__global__ __launch_bounds__(256) void k_beta(const float* __restrict__ ao,
                                              const float* __restrict__ xr,
                                              const float* __restrict__ Wb,
                                              float* __restrict__ bta) {
    int wave = threadIdx.x >> 6, lane = threadIdx.x & 63;
    int n = blockIdx.x * 4 + wave;
    const float* o = ao + (size_t)n * HDIM;
    const float* r = xr + (size_t)n * HDIM;
    float acc = 0.f;
#pragma unroll
    for (int i0 = 0; i0 < HDIM; i0 += 64) {
        int i = i0 + lane;
        float ov = o[i], rv = r[i];
        acc += ov * Wb[i] + rv * Wb[HDIM + i] + (ov - rv) * Wb[2 * HDIM + i];
    }
    acc = waveReduceSum(acc);
    if (lane == 0) bta[n] = 1.f / (1.f + expf(-acc));
}

__global__ void k_h2(const float* __restrict__ ao, const float* __restrict__ xr,
                     const float* __restrict__ bta, float* __restrict__ h2) {
    int i = blockIdx.x * 256 + threadIdx.x;  // NN*HDIM
    float b = bta[i >> 9];
    h2[i] = b * xr[i] + (1.f - b) * ao[i];
}

// ---------------- TopK pooling ----------------
__global__ __launch_bounds__(256) void k_pool_score(const float* __restrict__ h,
                                                    const float* __restrict__ w,
                                                    float* __restrict__ sv) {
    int wave = threadIdx.x >> 6, lane = threadIdx.x & 63;
    int n = blockIdx.x * 4 + wave;
    float w0 = w[lane], w1 = w[lane + 64];
    float n2 = waveReduceSum(w0 * w0 + w1 * w1);
    float dv = h[(size_t)n * FF + lane] * w0 + h[(size_t)n * FF + lane + 64] * w1;
    dv = waveReduceSum(dv);
    if (lane == 0) sv[n] = tanhf(dv / sqrtf(n2));
}

__global__ __launch_bounds__(256) void k_pool_rank(const float* __restrict__ sv,
                                                   int* __restrict__ nmask,
                                                   int* __restrict__ keep, int kc) {
    __shared__ float sm[NPGC];
    int g = blockIdx.x, t = threadIdx.x;
    int n = g * NPGC + t;
    int old = nmask[n];
    sm[t] = old ? sv[n] : -INFINITY;
    __syncthreads();
    float mys = sm[t];
    int rank = 0;
    for (int j = 0; j < NPGC; ++j) {
        float o = sm[j];
        rank += (o > mys) || (o == mys && j < t);  // stable argsort tie-break
    }
    int kp = (rank < kc) && old;
    keep[n] = kp;
    nmask[n] = kp;
}

__global__ void k_pool_scale(float* __restrict__ h, const float* __restrict__ sv,
                             const int* __restrict__ keep) {
    int i = blockIdx.x * 256 + threadIdx.x;  // NN*FF
    int n = i >> 7;
    h[i] *= sv[n] * (float)keep[n];
}

__global__ void k_emask_upd(int* __restrict__ emask, const int* __restrict__ keep,
                            const int* __restrict__ src, const int* __restrict__ dst) {
    int e = blockIdx.x * 256 + threadIdx.x;
    if (e < NEDGE) emask[e] = emask[e] && keep[src[e]] && keep[dst[e]];
}

__global__ __launch_bounds__(128) void k_readout(const float* __restrict__ h,
                                                 const int* __restrict__ keep,
                                                 float* __restrict__ rep) {
    int g = blockIdx.x, d = threadIdx.x;  // 128 threads = F dims
    float mx = -1e30f, smv = 0.f;
    int cnt = 0;
    for (int j = 0; j < NPGC; ++j) {
        int n = g * NPGC + j;
        int kp = keep[n];
        float val = h[(size_t)n * FF + d];
        if (kp) { mx = fmaxf(mx, val); smv += val; cnt++; }
    }
    rep[(size_t)g * 256 + d] = mx;
    rep[(size_t)g * 256 + 128 + d] = smv / fmaxf((float)cnt, 1.f);
}

// ---------------- readout head ----------------
__global__ void k_build_g(const float* __restrict__ r0, const float* __restrict__ r1,
                          const float* __restrict__ esm, float* __restrict__ g1) {
    int i = blockIdx.x * 256 + threadIdx.x;  // BB*1536
    int r = i / 1536, c = i % 1536;
    g1[i] = (c < 256) ? (r0[r * 256 + c] + r1[r * 256 + c]) : esm[r * ESMC + (c - 256)];
}

// wave-per-output MLP: one 64-lane wave computes one out[r][c] dot product.
// Replaces thread-per-output version that was latency-bound at 500 us
// (64-block grid, serial K=1536 dependent-FMA chain per thread).
__global__ __launch_bounds__(256) void k_mlp_wave(const float* __restrict__ A,
                                                  const float* __restrict__ W,
                                                  const float* __restrict__ b,
                                                  float* __restrict__ C,
                                                  int M, int N, int K, int relu) {
    int wid = (blockIdx.x * 256 + threadIdx.x) >> 6;
    int lane = threadIdx.x & 63;
    if (wid >= M * N) return;
    int r = wid / N, c = wid % N;
    const float* Arow = A + (size_t)r * K;
    float acc = 0.f;
    for (int kk = lane; kk < K; kk += 64)
        acc = fmaf(Arow[kk], W[(size_t)kk * N + c], acc);
    acc = waveReduceSum(acc);
    if (lane == 0) {
        acc += b[c];
        C[wid] = relu ? fmaxf(acc, 0.f) : acc;
    }
}

// ---------------- host launch ----------------
extern "C" void kernel_launch(void* const* d_in, const int* in_sizes, int n_in,
                              void* d_out, int out_size, void* d_ws, size_t ws_size,
                              hipStream_t stream) {
    const float* x = (const float*)d_in[0];
    const float* eattr = (const float*)d_in[1];
    const int* eidx = (const int*)d_in[2];
    const float* esm = (const float*)d_in[4];
    const float* Wq = (const float*)d_in[5];
    const float* bq = (const float*)d_in[6];
    const float* Wk = (const float*)d_in[7];
    const float* bk = (const float*)d_in[8];
    const float* Wv = (const float*)d_in[9];
    const float* bv = (const float*)d_in[10];
    const float* We = (const float*)d_in[11];
    const float* Wsk = (const float*)d_in[12];
    const float* bsk = (const float*)d_in[13];
    const float* Wbe = (const float*)d_in[14];
    const float* Wt = (const float*)d_in[15];
    const float* bt = (const float*)d_in[16];
    const float* gam = (const float*)d_in[17];
    const float* bet = (const float*)d_in[18];
    const float* rme = (const float*)d_in[19];
    const float* rva = (const float*)d_in[20];
    const float* pw = (const float*)d_in[21];
    const float* W1 = (const float*)d_in[22];
    const float* b1 = (const float*)d_in[23];
    const float* W2 = (const float*)d_in[24];
    const float* b2 = (const float*)d_in[25];
    const float* W3 = (const float*)d_in[26];
    const float* b3 = (const float*)d_in[27];
    const int* srcp = eidx;
    const int* dstp = eidx + NEDGE;

    char* p = (char*)d_ws;
    auto alloc = [&](size_t bytes) -> void* {
        void* r = (void*)p;
        p += (bytes + 255) & ~(size_t)255;
        return r;
    };
    float* hA = (float*)alloc((size_t)NNODE * FF * 4);
    float* hB = (float*)alloc((size_t)NNODE * FF * 4);
    float* qb = (float*)alloc((size_t)NNODE * HDIM * 4);
    float* kb = (float*)alloc((size_t)NNODE * HDIM * 4);
    float* vb = (float*)alloc((size_t)NNODE * HDIM * 4);
    float* xrb = (float*)alloc((size_t)NNODE * HDIM * 4);
    float* aob = (float*)alloc((size_t)NNODE * HDIM * 4);
    float* h2b = qb;  // q no longer needed once scores are done
    float* a_sc = (float*)alloc((size_t)NEDGE * NH * 4);
    float* mb = (float*)alloc((size_t)NNODE * NH * 4);
    float* db = (float*)alloc((size_t)NNODE * NH * 4);
    float* btab = (float*)alloc((size_t)NNODE * 4);
    float* sv = (float*)alloc((size_t)NNODE * 4);
    float* rep0 = (float*)alloc((size_t)BB * 256 * 4);
    float* rep1 = (float*)alloc((size_t)BB * 256 * 4);
    float* g1 = (float*)alloc((size_t)BB * 1536 * 4);
    float* g2 = (float*)alloc((size_t)BB * 512 * 4);
    float* g3 = (float*)alloc((size_t)BB * 256 * 4);
    int* nmask = (int*)alloc((size_t)NNODE * 4);
    int* emask = (int*)alloc((size_t)NEDGE * 4);
    int* keep = (int*)alloc((size_t)NNODE * 4);
    int* indeg = (int*)alloc((size_t)NNODE * 4);
    int* coff = (int*)alloc((size_t)(NNODE + 1) * 4);
    int* ccnt = (int*)alloc((size_t)NNODE * 4);
    int* ceid = (int*)alloc((size_t)NEDGE * 4);

    hipMemsetAsync(indeg, 0, (size_t)NNODE * 4, stream);
    hipMemsetAsync(ccnt, 0, (size_t)NNODE * 4, stream);
    k_init<<<NEDGE / 256, 256, 0, stream>>>(emask, nmask);
    k_count<<<NEDGE / 256, 256, 0, stream>>>(dstp, indeg);
    k_scan<<<1, 256, 0, stream>>>(indeg, coff);
    k_scatter<<<NEDGE / 256, 256, 0, stream>>>(dstp, coff, ccnt, ceid);

    auto conv = [&](int li, const float* hin, float* hout) {
        size_t wOff = (size_t)li * FF * HDIM;
        dim3 gq(NNODE / 128, HDIM / 128, 4);
        k_gemm<128, 128, 32, 8, 8, 0><<<gq, 256, 0, stream>>>(
            hin, Wq + wOff, Wk + wOff, Wv + wOff, Wsk + wOff,
            bq + li * HDIM, bk + li * HDIM, bv + li * HDIM, bsk + li * HDIM,
            qb, kb, vb, xrb, NNODE, HDIM, FF,
            nullptr, nullptr, nullptr, nullptr);
        const float* WeL = We + (size_t)li * EDIMC * HDIM;
        k_edge_scores<<<NEDGE / 16, 256, 0, stream>>>(qb, kb, eattr, WeL, srcp, dstp, emask, a_sc);
        k_softmax_md<<<NNODE * NH / 256, 256, 0, stream>>>(a_sc, coff, ceid, emask, mb, db);
        k_aggregate<<<NNODE, 256, 0, stream>>>(vb, eattr, WeL, a_sc, mb, db, srcp, coff, ceid,
                                               emask, aob);
        k_beta<<<NNODE / 4, 256, 0, stream>>>(aob, xrb, Wbe + (size_t)li * 3 * HDIM, btab);
        k_h2<<<NNODE * HDIM / 256, 256, 0, stream>>>(aob, xrb, btab, h2b);
        dim3 go(NNODE / 64, FF / 64, 1);
        k_gemm<64, 64, 32, 4, 4, 1><<<go, 256, 0, stream>>>(
            h2b, Wt + (size_t)li * HDIM * FF, nullptr, nullptr, nullptr,
            bt + li * FF, nullptr, nullptr, nullptr,
            hout, nullptr, nullptr, nullptr, NNODE, FF, HDIM,
            gam + li * FF, bet + li * FF, rme + li * FF, rva + li * FF);
    };

    auto pool = [&](int pi, float* h, float* rep, int kc, bool updEmask) {
        k_pool_score<<<NNODE / 4, 256, 0, stream>>>(h, pw + pi * FF, sv);
        k_pool_rank<<<BB, 256, 0, stream>>>(sv, nmask, keep, kc);
        k_pool_scale<<<NNODE * FF / 256, 256, 0, stream>>>(h, sv, keep);
        if (updEmask) k_emask_upd<<<NEDGE / 256, 256, 0, stream>>>(emask, keep, srcp, dstp);
        k_readout<<<BB, 128, 0, stream>>>(h, keep, rep);
    };

    // layer 4 (li=4) is dead code in the reference (its output feeds nothing) — skipped.
    conv(0, x, hA);
    conv(1, hA, hB);
    pool(0, hB, rep0, NPGC / 2, true);
    conv(2, hB, hA);
    conv(3, hA, hB);
    pool(1, hB, rep1, NPGC / 4, false);  // emask update after pool-1 is also dead

    k_build_g<<<BB * 1536 / 256, 256, 0, stream>>>(rep0, rep1, esm, g1);
    // wave-per-output MLP head: 4096 / 2048 / 80 blocks — latency hidden by TLP.
    k_mlp_wave<<<(BB * 512 * 64) / 256, 256, 0, stream>>>(g1, W1, b1, g2, BB, 512, 1536, 1);
    k_mlp_wave<<<(BB * 256 * 64) / 256, 256, 0, stream>>>(g2, W2, b2, g3, BB, 256, 512, 1);
    k_mlp_wave<<<(BB * 10 * 64 + 255) / 256, 256, 0, stream>>>(g3, W3, b3, (float*)d_out, BB, 10, 256, 0);
}